// Round 7
// baseline (243.790 us; speedup 1.0000x reference)
//
#include <hip/hip_runtime.h>
#include <cstdint>

// B=16384, D=512, U=512, K=D+U=1024, N=4U=2048
#define HU 8388608  // 16384*512, offset of c-part in out

typedef __attribute__((ext_vector_type(8))) short short8_t;
typedef __attribute__((ext_vector_type(4))) float float4_t;
typedef __attribute__((ext_vector_type(16))) float float16_t;
typedef __attribute__((ext_vector_type(4))) unsigned int uint4_t;
typedef __attribute__((ext_vector_type(2))) unsigned int uint2_t;

__device__ __forceinline__ unsigned short f2bf(float x) {
    unsigned u = __builtin_bit_cast(unsigned, x);
    u += 0x7fffu + ((u >> 16) & 1u);  // RNE
    return (unsigned short)(u >> 16);
}

__device__ __forceinline__ void gll16(const void* g, const void* lds) {
    __builtin_amdgcn_global_load_lds(
        (const __attribute__((address_space(1))) unsigned int*)(uintptr_t)g,
        (__attribute__((address_space(3))) unsigned int*)(unsigned int)(uintptr_t)lds,
        16, 0, 0);
}

__device__ __forceinline__ float sigm(float x) {
    return __builtin_amdgcn_rcpf(1.f + __expf(-x));
}
__device__ __forceinline__ float tanhfast(float x) {
    float ax = fabsf(x);
    float e = __expf(-2.f * ax);
    float r = (1.f - e) * __builtin_amdgcn_rcpf(1.f + e);
    return copysignf(r, x);
}

// ---------- pre-pass (R4 proven): 2048 fat blocks; concat x4 + one transpose tile ----------
__global__ __launch_bounds__(256) void prep(const float* __restrict__ x,
                                            const float* __restrict__ h,
                                            const float* __restrict__ W,
                                            const float* __restrict__ R,
                                            unsigned short* __restrict__ xh,
                                            unsigned short* __restrict__ btw) {
    __shared__ float t[32 * 33];
    int bid = blockIdx.x;
    int tid = threadIdx.x;

#pragma unroll
    for (int i = 0; i < 4; ++i) {
        int n = (i * 2048 + bid) * 256 + tid;
        int e8 = n * 8;
        int row = e8 >> 10, col = e8 & 1023;
        const float* src = (col < 512) ? (x + (size_t)row * 512 + col)
                                       : (h + (size_t)row * 512 + (col - 512));
        float4_t lo = *(const float4_t*)src;
        float4_t hi = *(const float4_t*)(src + 4);
        uint4_t o;
        o.x = (unsigned)f2bf(lo.x) | ((unsigned)f2bf(lo.y) << 16);
        o.y = (unsigned)f2bf(lo.z) | ((unsigned)f2bf(lo.w) << 16);
        o.z = (unsigned)f2bf(hi.x) | ((unsigned)f2bf(hi.y) << 16);
        o.w = (unsigned)f2bf(hi.z) | ((unsigned)f2bf(hi.w) << 16);
        *(uint4_t*)(xh + e8) = o;
    }

    // transpose: gate-major btw[n''][k] = bf16(Wall[k][g*512+u]), n'' = ub*128 + g*32 + uo
    int kt = bid & 31, ub = (bid >> 5) & 15, g = bid >> 9;
    int ky = tid >> 3, ux4 = (tid & 7) * 4;
    int kg = kt * 32 + ky;
    int col = g * 512 + ub * 32 + ux4;
    const float* src = (kg < 512) ? (W + (size_t)kg * 2048 + col)
                                  : (R + (size_t)(kg - 512) * 2048 + col);
    float4_t v = *(const float4_t*)src;
    t[ky * 33 + ux4 + 0] = v.x;
    t[ky * 33 + ux4 + 1] = v.y;
    t[ky * 33 + ux4 + 2] = v.z;
    t[ky * 33 + ux4 + 3] = v.w;
    __syncthreads();
    int uo = tid >> 3, kx4 = (tid & 7) * 4;
    unsigned short o0 = f2bf(t[(kx4 + 0) * 33 + uo]);
    unsigned short o1 = f2bf(t[(kx4 + 1) * 33 + uo]);
    unsigned short o2 = f2bf(t[(kx4 + 2) * 33 + uo]);
    unsigned short o3 = f2bf(t[(kx4 + 3) * 33 + uo]);
    uint2_t p;
    p.x = (unsigned)o0 | ((unsigned)o1 << 16);
    p.y = (unsigned)o2 | ((unsigned)o3 << 16);
    *(uint2_t*)(btw + (size_t)(ub * 128 + g * 32 + uo) * 1024 + kt * 32 + kx4) = p;
}

// ---------- main: 128x128 tile, BK=32, 4 waves, acc=64 regs -> 3 waves/SIMD ----------
// THE change vs rounds 1-6: per-wave output 32x128 (1 M-frag x 4 gates) halves the
// accumulator to 64 regs; with ~100 arch regs, 3 waves/SIMD fit under (256,3).
// 48 KB ring-3 LDS x 3 blocks = 144 <= 160 KB -> THREE independent blocks/CU:
// cross-block TLP fills barrier/vmcnt stalls (R5's version of this failed only
// because 236 regs/wave capped HW at 2 waves/SIMD regardless of block shape).
// Ring-3 + counted vmcnt(4): per-wave count before the shared barrier => all waves'
// next-tile loads retired at barrier exit. Same XOR row-pair LDS layout as R2-R6
// (stage rowpairs have rp&7 == lane>>3, so global chunk g = (lane&7)^(lane>>3)).

#define MFMA(va, vb, vc) __builtin_amdgcn_mfma_f32_32x32x16_bf16(va, vb, vc, 0, 0, 0)

#define STAGE(T)                                            \
    do {                                                    \
        const int _so = ((T) % 3) * 8192;                   \
        gll16(aSrc0 + (T) * 32, &lds[_so + dA0]);           \
        gll16(aSrc1 + (T) * 32, &lds[_so + dA1]);           \
        gll16(bSrc0 + (T) * 32, &lds[_so + dB0]);           \
        gll16(bSrc1 + (T) * 32, &lds[_so + dB1]);           \
    } while (0)

__global__ __launch_bounds__(256, 3) void lstm_main(
    const unsigned short* __restrict__ xh,   // [16384][1024] bf16
    const unsigned short* __restrict__ btw,  // [2048][1024] bf16, gate-major rows
    const float* __restrict__ c_tm1,         // [16384][512]
    const float* __restrict__ pw,            // [512][3]
    const float* __restrict__ bias,          // [2048]
    float* __restrict__ out)                 // [2][16384][512]
{
    __shared__ __align__(16) short lds[24576];  // 48 KB: 3 slots x (A 8KB + B 8KB)

    int tid = threadIdx.x;
    int lane = tid & 63, w = tid >> 6;       // 4 waves stacked along M
    int l31 = lane & 31, hfl = lane >> 5;

    // XCD-aware swizzle: 2048 blocks; each XCD gets 16 mb x 16 nb (B-panel reused by
    // 16 consecutive blocks within an XCD; whole btw = 4 MB fits one XCD L2)
    int bid = blockIdx.x;
    int xcd = bid & 7, local = bid >> 3;     // local in [0,256)
    int mb = xcd * 16 + (local & 15);        // [0,128)
    int nb = local >> 4;                     // [0,16) == gate-major ub group

    // ---- staging: linear LDS dest (gll16), pre-swizzled per-lane global source ----
    // rowpairs rp = w*16 + {0,8} + (lane>>3): rp&7 == lane>>3 for both, so the
    // chunk permutation is g = (lane&7) ^ (lane>>3) for all four loads.
    int lr = lane >> 3, sl = lane & 7;
    int g = sl ^ lr;
    int rpa0 = w * 16 + lr, rpa1 = w * 16 + 8 + lr;
    const unsigned short* aSrc0 = xh + (size_t)(mb * 128 + 2 * rpa0 + (g >> 2)) * 1024 + (g & 3) * 8;
    const unsigned short* aSrc1 = xh + (size_t)(mb * 128 + 2 * rpa1 + (g >> 2)) * 1024 + (g & 3) * 8;
    const unsigned short* bSrc0 = btw + (size_t)(nb * 128 + 2 * rpa0 + (g >> 2)) * 1024 + (g & 3) * 8;
    const unsigned short* bSrc1 = btw + (size_t)(nb * 128 + 2 * rpa1 + (g >> 2)) * 1024 + (g & 3) * 8;
    int dA0 = w * 1024 + lane * 8;           // = rpa0*64 + sl*8, linear in lane
    int dA1 = dA0 + 512;
    int dB0 = 4096 + dA0, dB1 = 4096 + dA1;

    // ---- read offsets (shorts within slot): frag(r, c2) at rp*64 + s*8,
    //      s = (4*(r&1) + c2) ^ (rp&7), c2 = jj*2 + hfl
    int aro0, aro1, bro[4][2];
    {
        int r = w * 32 + l31, rp = r >> 1;
        aro0 = rp * 64 + (((4 * (r & 1) + 0 * 2 + hfl) ^ (rp & 7)) * 8);
        aro1 = rp * 64 + (((4 * (r & 1) + 1 * 2 + hfl) ^ (rp & 7)) * 8);
    }
#pragma unroll
    for (int g4 = 0; g4 < 4; ++g4) {
        int r = g4 * 32 + l31, rp = r >> 1;
#pragma unroll
        for (int jj = 0; jj < 2; ++jj) {
            int s = (4 * (r & 1) + jj * 2 + hfl) ^ (rp & 7);
            bro[g4][jj] = 4096 + rp * 64 + s * 8;
        }
    }

    float16_t acc[4];
#pragma unroll
    for (int g4 = 0; g4 < 4; ++g4)
#pragma unroll
        for (int r = 0; r < 16; ++r) acc[g4][r] = 0.f;

    // ---- prologue: stage tiles 0,1; retire tile 0 (8 in flight -> 4) ----
    STAGE(0);
    STAGE(1);
    asm volatile("s_waitcnt vmcnt(4)" ::: "memory");
    __builtin_amdgcn_s_barrier();
    asm volatile("" ::: "memory");

    // ---- main loop: stage t+2 (slot (t+2)%3), read slot t%3, vmcnt(4), barrier ----
#pragma unroll
    for (int t = 0; t < 32; ++t) {
        const int ro = (t % 3) * 8192;
        if (t < 30) STAGE(t + 2);
        short8_t a0  = *(const short8_t*)&lds[ro + aro0];
        short8_t a1  = *(const short8_t*)&lds[ro + aro1];
        short8_t b00 = *(const short8_t*)&lds[ro + bro[0][0]];
        short8_t b10 = *(const short8_t*)&lds[ro + bro[1][0]];
        short8_t b20 = *(const short8_t*)&lds[ro + bro[2][0]];
        short8_t b30 = *(const short8_t*)&lds[ro + bro[3][0]];
        short8_t b01 = *(const short8_t*)&lds[ro + bro[0][1]];
        short8_t b11 = *(const short8_t*)&lds[ro + bro[1][1]];
        short8_t b21 = *(const short8_t*)&lds[ro + bro[2][1]];
        short8_t b31 = *(const short8_t*)&lds[ro + bro[3][1]];
        __builtin_amdgcn_s_setprio(1);
        acc[0] = MFMA(a0, b00, acc[0]);
        acc[1] = MFMA(a0, b10, acc[1]);
        acc[2] = MFMA(a0, b20, acc[2]);
        acc[3] = MFMA(a0, b30, acc[3]);
        acc[0] = MFMA(a1, b01, acc[0]);
        acc[1] = MFMA(a1, b11, acc[1]);
        acc[2] = MFMA(a1, b21, acc[2]);
        acc[3] = MFMA(a1, b31, acc[3]);
        __builtin_amdgcn_s_setprio(0);
        if (t < 30) {
            asm volatile("s_waitcnt vmcnt(4)" ::: "memory");
        } else if (t == 30) {
            asm volatile("s_waitcnt vmcnt(0)" ::: "memory");
        }
        if (t < 31) {
            __builtin_amdgcn_s_barrier();
            asm volatile("" ::: "memory");
        }
    }

    // ---- register epilogue: lane holds all 4 gates of (row, unit) in acc[0..3] ----
    // 32x32 C/D: col=lane&31 (unit), row=(reg&3)+8*(reg>>2)+4*(lane>>5)
    int u = nb * 32 + l31;
    float bi = bias[u], bf = bias[512 + u], bg2 = bias[1024 + u], bo2 = bias[1536 + u];
    float pwi = pw[u * 3 + 0], pwf = pw[u * 3 + 1], pwo = pw[u * 3 + 2];
    int rbase = mb * 128 + w * 32 + 4 * hfl;
#pragma unroll
    for (int reg = 0; reg < 16; ++reg) {
        int grow = rbase + (reg & 3) + 8 * (reg >> 2);
        size_t off = (size_t)grow * 512 + u;
        float c1 = c_tm1[off];
        float iv = sigm(acc[0][reg] + bi + c1 * pwi);
        float fv = sigm(acc[1][reg] + bf + c1 * pwf);
        float gv = tanhfast(acc[2][reg] + bg2);
        float cc = fv * c1 + iv * gv;
        float ov = sigm(acc[3][reg] + bo2 + cc * pwo);
        out[off] = ov * tanhfast(cc);
        out[HU + off] = cc;
    }
}

extern "C" void kernel_launch(void* const* d_in, const int* in_sizes, int n_in,
                              void* d_out, int out_size, void* d_ws, size_t ws_size,
                              hipStream_t stream) {
    const float* x    = (const float*)d_in[0];
    const float* h    = (const float*)d_in[1];
    const float* c    = (const float*)d_in[2];
    const float* W    = (const float*)d_in[3];
    const float* R    = (const float*)d_in[4];
    const float* pw   = (const float*)d_in[5];
    const float* bias = (const float*)d_in[6];
    float* out = (float*)d_out;

    unsigned short* xh  = (unsigned short*)d_ws;                        // 33,554,432 B
    unsigned short* btw = (unsigned short*)((char*)d_ws + 33554432u);   // + 4,194,304 B

    prep<<<2048, 256, 0, stream>>>(x, h, W, R, xh, btw);
    lstm_main<<<2048, 256, 0, stream>>>(xh, btw, c, pw, bias, out);
}